// Round 5
// baseline (410.704 us; speedup 1.0000x reference)
//
#include <hip/hip_runtime.h>
#include <math.h>

// MHA forward: B=4, S=2048, E=1024, H=16, D=64. bf16 MFMA path.
// Round 5: all-bf16 GEMMs (X pre-converted into d_out/Ax scratch — zero extra
// ws), N-tile-fast grid order for L2 A-reuse, attention one-q-tile-per-block
// longest-first (2048 balanced-ish blocks, 8/CU).

#define EMBED 1024
#define SEQ   2048
#define NH    16
#define HD    64
#define QSCALE 0.18033688011112042f   // 0.125 * log2(e), folded into Q proj

typedef __attribute__((ext_vector_type(4))) float f32x4;
typedef __attribute__((ext_vector_type(8))) short s16x8;
typedef __attribute__((ext_vector_type(4))) short s16x4;
typedef __attribute__((ext_vector_type(2))) unsigned int u32x2;

#define GLDS16(gp, lp) __builtin_amdgcn_global_load_lds( \
    (const __attribute__((address_space(1))) void*)(gp), \
    (__attribute__((address_space(3))) void*)(lp), 16, 0, 0)

__device__ __forceinline__ unsigned short f2bf(float f) {   // RNE
    unsigned int u = __builtin_bit_cast(unsigned int, f);
    u += 0x7fffu + ((u >> 16) & 1u);
    return (unsigned short)(u >> 16);
}
// pack two fp32 -> bf16x2 dword by truncation (1 v_perm_b32)
__device__ __forceinline__ unsigned int pkbf(float lo, float hi) {
    return __builtin_amdgcn_perm(__builtin_bit_cast(unsigned int, hi),
                                 __builtin_bit_cast(unsigned int, lo),
                                 0x07060302u);
}

// ---------------- fp32 -> bf16 (RNE): 3 X tensors + 4 weights ---------------
struct CvtArgs { const float* s[7]; unsigned short* d[7]; };
__global__ void cvt_all(CvtArgs ca)
{
    const int y = blockIdx.y;
    const int n4 = (y < 3) ? (1 << 21) : (1 << 18);   // f32x4 count
    int i = blockIdx.x * 256 + threadIdx.x;
    if (i < n4) {
        f32x4 v = *(const f32x4*)(ca.s[y] + (size_t)i * 4);
        s16x4 p;
        p[0] = (short)f2bf(v[0]); p[1] = (short)f2bf(v[1]);
        p[2] = (short)f2bf(v[2]); p[3] = (short)f2bf(v[3]);
        *(s16x4*)(ca.d[y] + (size_t)i * 4) = p;
    }
}

// ---------------- QKV projection (z = 0:Q, 1:K, 2:V), all-bf16 --------------
// C[m,n] = X[m,:] . W[n,:] + bias[n]
// Q/K scatter -> bf16 [B][H][S][D]; V scatter -> V^T bf16 [B][H][D][S].
// Q additionally scaled by QSCALE (softmax in exp2 domain).
struct ProjArgs {
    const unsigned short* X[3];
    const unsigned short* W[3];
    const float* Bz[3];
    unsigned short* Oz[3];
};
__global__ void __launch_bounds__(256)
gemm_qkv(ProjArgs pa)
{
    __shared__ unsigned short Ab[128 * 64];
    __shared__ unsigned short Bb[128 * 64];
    const int z = blockIdx.z;
    const unsigned short* Xb = pa.X[z];
    const unsigned short* Wb = pa.W[z];
    const float* bias = pa.Bz[z];
    unsigned short* Out = pa.Oz[z];
    const float scale = (z == 0) ? QSCALE : 1.0f;
    const int tid = threadIdx.x, lane = tid & 63, wv = tid >> 6;
    const int g = lane >> 4, c = lane & 15;
    const int wx = wv & 1, wy = wv >> 1;
    const int bn0 = blockIdx.x * 128, bm0 = blockIdx.y * 128;  // N fast for L2

    f32x4 acc[4][4];
#pragma unroll
    for (int i = 0; i < 4; ++i)
#pragma unroll
        for (int n = 0; n < 4; ++n) acc[i][n] = f32x4{0.f, 0.f, 0.f, 0.f};

    for (int k0 = 0; k0 < EMBED; k0 += 64) {
        __syncthreads();
#pragma unroll
        for (int cc = 0; cc < 4; ++cc) {
            int li = cc * 256 + tid;
            int row = li >> 3, ch = (li & 7) ^ (row & 7);
            GLDS16(Xb + (size_t)(bm0 + row) * EMBED + k0 + ch * 8,
                   Ab + cc * 2048 + wv * 512);
        }
#pragma unroll
        for (int cc = 0; cc < 4; ++cc) {
            int li = cc * 256 + tid;
            int row = li >> 3, ch = (li & 7) ^ (row & 7);
            GLDS16(Wb + (size_t)(bn0 + row) * EMBED + k0 + ch * 8,
                   Bb + cc * 2048 + wv * 512);
        }
        __syncthreads();
#pragma unroll
        for (int ks = 0; ks < 2; ++ks) {
            const int ib = ((ks * 4 + g) ^ (c & 7)) * 8;
            s16x8 af[4], bfr[4];
#pragma unroll
            for (int i = 0; i < 4; ++i)
                af[i] = *(const s16x8*)(&Ab[(wy * 64 + i * 16 + c) * 64 + ib]);
#pragma unroll
            for (int n = 0; n < 4; ++n)
                bfr[n] = *(const s16x8*)(&Bb[(wx * 64 + n * 16 + c) * 64 + ib]);
#pragma unroll
            for (int i = 0; i < 4; ++i)
#pragma unroll
                for (int n = 0; n < 4; ++n)
                    acc[i][n] = __builtin_amdgcn_mfma_f32_16x16x32_bf16(af[i], bfr[n], acc[i][n], 0, 0, 0);
        }
    }
    if (z < 2) {        // Q/K -> [B][H][S][D]
#pragma unroll
        for (int i = 0; i < 4; ++i) {
            int m0 = bm0 + wy * 64 + i * 16 + g * 4;
            int bb = m0 >> 11, s0 = m0 & 2047;
#pragma unroll
            for (int n = 0; n < 4; ++n) {
                int ncol = bn0 + wx * 64 + n * 16 + c;
                float bv = bias[ncol];
                int hh = ncol >> 6, dd = ncol & 63;
                size_t base = (((size_t)bb * NH + hh) * SEQ + s0) * HD + dd;
#pragma unroll
                for (int r = 0; r < 4; ++r)
                    Out[base + (size_t)r * HD] = f2bf((acc[i][n][r] + bv) * scale);
            }
        }
    } else {            // V -> V^T [B][H][D][S], 8B stores
#pragma unroll
        for (int i = 0; i < 4; ++i) {
            int m0 = bm0 + wy * 64 + i * 16 + g * 4;
            int bb = m0 >> 11, s0 = m0 & 2047;
#pragma unroll
            for (int n = 0; n < 4; ++n) {
                int ncol = bn0 + wx * 64 + n * 16 + c;
                float bv = bias[ncol];
                int hh = ncol >> 6, dd = ncol & 63;
                s16x4 pk;
#pragma unroll
                for (int r = 0; r < 4; ++r) pk[r] = (short)f2bf(acc[i][n][r] + bv);
                *(s16x4*)(&Out[(((size_t)bb * NH + hh) * HD + dd) * SEQ + s0]) = pk;
            }
        }
    }
}

// ---------------- output projection -----------------------------------------
__global__ void __launch_bounds__(256)
gemm_out(const unsigned short* __restrict__ Xb, const unsigned short* __restrict__ Wb,
         const float* __restrict__ bias, float* __restrict__ Out)
{
    __shared__ unsigned short Ab[128 * 64];
    __shared__ unsigned short Bb[128 * 64];
    const int tid = threadIdx.x;
    const int lane = tid & 63, wv = tid >> 6;
    const int g = lane >> 4, c = lane & 15;
    const int wx = wv & 1, wy = wv >> 1;
    const int bn0 = blockIdx.x * 128, bm0 = blockIdx.y * 128;  // N fast

    f32x4 acc[4][4];
#pragma unroll
    for (int i = 0; i < 4; ++i)
#pragma unroll
        for (int n = 0; n < 4; ++n) acc[i][n] = f32x4{0.f, 0.f, 0.f, 0.f};

    for (int k0 = 0; k0 < EMBED; k0 += 64) {
        __syncthreads();
#pragma unroll
        for (int cc = 0; cc < 4; ++cc) {
            int li = cc * 256 + tid;
            int row = li >> 3, ch = (li & 7) ^ (row & 7);
            GLDS16(Xb + (size_t)(bm0 + row) * EMBED + k0 + ch * 8,
                   Ab + cc * 2048 + wv * 512);
        }
#pragma unroll
        for (int cc = 0; cc < 4; ++cc) {
            int li = cc * 256 + tid;
            int row = li >> 3, ch = (li & 7) ^ (row & 7);
            GLDS16(Wb + (size_t)(bn0 + row) * EMBED + k0 + ch * 8,
                   Bb + cc * 2048 + wv * 512);
        }
        __syncthreads();
#pragma unroll
        for (int ks = 0; ks < 2; ++ks) {
            const int ib = ((ks * 4 + g) ^ (c & 7)) * 8;
            s16x8 af[4], bfr[4];
#pragma unroll
            for (int i = 0; i < 4; ++i)
                af[i] = *(const s16x8*)(&Ab[(wy * 64 + i * 16 + c) * 64 + ib]);
#pragma unroll
            for (int n = 0; n < 4; ++n)
                bfr[n] = *(const s16x8*)(&Bb[(wx * 64 + n * 16 + c) * 64 + ib]);
#pragma unroll
            for (int i = 0; i < 4; ++i)
#pragma unroll
                for (int n = 0; n < 4; ++n)
                    acc[i][n] = __builtin_amdgcn_mfma_f32_16x16x32_bf16(af[i], bfr[n], acc[i][n], 0, 0, 0);
        }
    }
#pragma unroll
    for (int i = 0; i < 4; ++i) {
#pragma unroll
        for (int n = 0; n < 4; ++n) {
            int ncol = bn0 + wx * 64 + n * 16 + c;
            float bv = bias[ncol];
#pragma unroll
            for (int r = 0; r < 4; ++r) {
                int m = bm0 + wy * 64 + i * 16 + g * 4 + r;
                Out[(size_t)m * EMBED + ncol] = acc[i][n][r] + bv;
            }
        }
    }
}

// ---------------- causal flash attention (S^T layout, dbuf prefetch) --------
// grid (32, NH, B); one 64-row q-tile per block, longest-first (qt = 31-bx).
__global__ void __launch_bounds__(256)
attn_fwd(const unsigned short* __restrict__ Qb, const unsigned short* __restrict__ Kb,
         const unsigned short* __restrict__ Vg, unsigned short* __restrict__ Ob)
{
    __shared__ unsigned short Kt[2][64 * 64];  // K tile [s][d], swizzled
    __shared__ unsigned short Vt[2][64 * 64];  // V^T tile [d][s], swizzled
    __shared__ unsigned int   Pb[4][16 * 36];  // per-wave P, dwords, stride 36
    const int tid = threadIdx.x, lane = tid & 63, wv = tid >> 6;
    const int g = lane >> 4, c = lane & 15;
    const int h = blockIdx.y, b = blockIdx.z;
    const size_t bh = (size_t)b * NH + h;
    const unsigned short* K0 = Kb + bh * SEQ * HD;
    const unsigned short* V0 = Vg + bh * HD * SEQ;
    unsigned int* Pw = &Pb[wv][0];
    const int x0 = (g ^ (c & 7)) * 8;          // swizzled chunk offsets
    const int x1 = ((4 + g) ^ (c & 7)) * 8;
    // hoisted staging source offsets (swizzled)
    const int li0 = tid, li1 = 256 + tid;
    const int kr0 = (li0 >> 3) * HD + (((li0 & 7) ^ ((li0 >> 3) & 7)) << 3);
    const int kr1 = (li1 >> 3) * HD + (((li1 & 7) ^ ((li1 >> 3) & 7)) << 3);
    const int vr0 = (li0 >> 3) * SEQ + (((li0 & 7) ^ ((li0 >> 3) & 7)) << 3);
    const int vr1 = (li1 >> 3) * SEQ + (((li1 & 7) ^ ((li1 >> 3) & 7)) << 3);

    const int qt = (SEQ / 64 - 1) - blockIdx.x;    // longest blocks dispatch first
    const unsigned short* Qp = Qb + (bh * SEQ + qt * 64 + wv * 16) * HD;
    s16x8 qf0 = *(const s16x8*)(Qp + c * HD + g * 8);
    s16x8 qf1 = *(const s16x8*)(Qp + c * HD + 32 + g * 8);
    f32x4 o[4];
#pragma unroll
    for (int dt = 0; dt < 4; ++dt) o[dt] = f32x4{0.f, 0.f, 0.f, 0.f};
    float m_run = -INFINITY, l_run = 0.f;

    {   // prologue: stage kt=0 into buffer 0
        GLDS16(K0 + kr0, &Kt[0][0] + wv * 512);
        GLDS16(K0 + kr1, &Kt[0][2048] + wv * 512);
        GLDS16(V0 + vr0, &Vt[0][0] + wv * 512);
        GLDS16(V0 + vr1, &Vt[0][2048] + wv * 512);
    }

    for (int kt = 0; kt <= qt; ++kt) {
        __syncthreads();           // publishes buffer kt&1 (drains GLDS)
        const int cur = kt & 1;
        if (kt < qt) {             // prefetch kt+1 into the other buffer
            const int nxt = cur ^ 1;
            const unsigned short* Kg = K0 + (size_t)(kt + 1) * 64 * HD;
            GLDS16(Kg + kr0, &Kt[nxt][0] + wv * 512);
            GLDS16(Kg + kr1, &Kt[nxt][2048] + wv * 512);
            const unsigned short* Vp = V0 + (kt + 1) * 64;
            GLDS16(Vp + vr0, &Vt[nxt][0] + wv * 512);
            GLDS16(Vp + vr1, &Vt[nxt][2048] + wv * 512);
        }
        const unsigned short* Kc = &Kt[cur][0];
        const unsigned short* Vc = &Vt[cur][0];

        const int ntmax = (kt == qt) ? wv : 3;   // skip fully-masked k-subtiles
        f32x4 sc[4];
#pragma unroll
        for (int nt = 0; nt < 4; ++nt) {
            if (nt <= ntmax) {
                f32x4 a = f32x4{0.f, 0.f, 0.f, 0.f};
                s16x8 kf0 = *(const s16x8*)(&Kc[(nt * 16 + c) * 64 + x0]);
                s16x8 kf1 = *(const s16x8*)(&Kc[(nt * 16 + c) * 64 + x1]);
                a = __builtin_amdgcn_mfma_f32_16x16x32_bf16(kf0, qf0, a, 0, 0, 0);
                a = __builtin_amdgcn_mfma_f32_16x16x32_bf16(kf1, qf1, a, 0, 0, 0);
                sc[nt] = a;
            } else {
                sc[nt] = f32x4{-INFINITY, -INFINITY, -INFINITY, -INFINITY};
            }
        }
        if (kt == qt) {   // diagonal tile: mask k > q
#pragma unroll
            for (int nt = 0; nt < 4; ++nt)
#pragma unroll
                for (int r = 0; r < 4; ++r)
                    if (nt * 16 + g * 4 + r > wv * 16 + c) sc[nt][r] = -INFINITY;
        }
        // online softmax: lane owns q-column c; k spread over regs+g
        float mloc = -INFINITY;
#pragma unroll
        for (int nt = 0; nt < 4; ++nt)
            mloc = fmaxf(mloc, fmaxf(fmaxf(sc[nt][0], sc[nt][1]),
                                     fmaxf(sc[nt][2], sc[nt][3])));
        mloc = fmaxf(mloc, __shfl_xor(mloc, 16));
        mloc = fmaxf(mloc, __shfl_xor(mloc, 32));
        if (__any(mloc > m_run)) {   // wave-uniform: new max somewhere
            float mnew = fmaxf(m_run, mloc);
            float alpha = __builtin_amdgcn_exp2f(m_run - mnew);
            m_run = mnew;
            l_run *= alpha;
            float av[4];
#pragma unroll
            for (int r = 0; r < 4; ++r) av[r] = __shfl(alpha, g * 4 + r, 16);
#pragma unroll
            for (int dt = 0; dt < 4; ++dt)
#pragma unroll
                for (int r = 0; r < 4; ++r) o[dt][r] *= av[r];
        }
        float rs = 0.f;
#pragma unroll
        for (int nt = 0; nt < 4; ++nt)
#pragma unroll
            for (int r = 0; r < 4; ++r) {
                float p = __builtin_amdgcn_exp2f(sc[nt][r] - m_run);
                sc[nt][r] = p;
                rs += p;
            }
        rs += __shfl_xor(rs, 16);
        rs += __shfl_xor(rs, 32);
        l_run += rs;
        // P^T (C-layout) -> P A-layout via wave-private packed LDS
#pragma unroll
        for (int nt = 0; nt < 4; ++nt) {
            u32x2 w;
            w[0] = pkbf(sc[nt][0], sc[nt][1]);
            w[1] = pkbf(sc[nt][2], sc[nt][3]);
            *(u32x2*)(&Pw[c * 36 + nt * 8 + g * 2]) = w;
        }
#pragma unroll
        for (int kc = 0; kc < 2; ++kc) {
            s16x8 pf = *(const s16x8*)(&Pw[c * 36 + kc * 16 + g * 4]);
            const int xv = kc ? x1 : x0;
#pragma unroll
            for (int dt = 0; dt < 4; ++dt) {
                s16x8 vf = *(const s16x8*)(&Vc[(dt * 16 + c) * 64 + xv]);
                o[dt] = __builtin_amdgcn_mfma_f32_16x16x32_bf16(pf, vf, o[dt], 0, 0, 0);
            }
        }
    }
    // epilogue: normalize rows, write [B][S][E] bf16
    float linv = 1.0f / l_run;
    float lv[4];
#pragma unroll
    for (int r = 0; r < 4; ++r) lv[r] = __shfl(linv, g * 4 + r, 16);
#pragma unroll
    for (int r = 0; r < 4; ++r) {
        int srow = qt * 64 + wv * 16 + g * 4 + r;
        size_t base = ((size_t)b * SEQ + srow) * EMBED + h * HD;
#pragma unroll
        for (int dt = 0; dt < 4; ++dt)
            Ob[base + dt * 16 + c] = f2bf(o[dt][r] * lv[r]);
    }
}

extern "C" void kernel_launch(void* const* d_in, const int* in_sizes, int n_in,
                              void* d_out, int out_size, void* d_ws, size_t ws_size,
                              hipStream_t stream)
{
    (void)in_sizes; (void)n_in; (void)out_size; (void)ws_size;
    const float* Xq = (const float*)d_in[0];
    const float* Xk = (const float*)d_in[1];
    const float* Xv = (const float*)d_in[2];
    // d_in[3] = attn_mask: tril(ones) -> causal handled analytically
    const float* Wq = (const float*)d_in[4];
    const float* bq = (const float*)d_in[5];
    const float* Wk = (const float*)d_in[6];
    const float* bk = (const float*)d_in[7];
    const float* Wv = (const float*)d_in[8];
    const float* bv = (const float*)d_in[9];
    const float* Wo = (const float*)d_in[10];
    const float* bo = (const float*)d_in[11];
    float* Out = (float*)d_out;

    unsigned short* ws = (unsigned short*)d_ws;
    unsigned short* wqb = ws;                    // 4 x 1M elts (weights bf16)
    unsigned short* wkb = wqb + 1048576;
    unsigned short* wvb = wkb + 1048576;
    unsigned short* wob = wvb + 1048576;
    unsigned short* Qb  = wob + 1048576;         // [B][H][S][D] bf16
    unsigned short* Kb  = Qb + 8388608;          // [B][H][S][D] bf16
    unsigned short* Vb  = Kb + 8388608;          // [B][H][D][S] bf16 (V^T)
    unsigned short* Ax  = Vb + 8388608;          // attn out bf16 [B][S][E] / Xv_b
    // bf16 X scratch overlaid on d_out (dead until gemm_out) and Ax (dead
    // until attn): Xq_b = d_out[0:8M], Xk_b = d_out[8M:16M], Xv_b = Ax.
    unsigned short* Xqb = (unsigned short*)d_out;
    unsigned short* Xkb = Xqb + 8388608;
    unsigned short* Xvb = Ax;

    CvtArgs ca;
    ca.s[0] = Xq; ca.s[1] = Xk; ca.s[2] = Xv;
    ca.s[3] = Wq; ca.s[4] = Wk; ca.s[5] = Wv; ca.s[6] = Wo;
    ca.d[0] = Xqb; ca.d[1] = Xkb; ca.d[2] = Xvb;
    ca.d[3] = wqb; ca.d[4] = wkb; ca.d[5] = wvb; ca.d[6] = wob;
    cvt_all<<<dim3(8192, 7), 256, 0, stream>>>(ca);

    ProjArgs pa;
    pa.X[0] = Xqb; pa.X[1] = Xkb; pa.X[2] = Xvb;
    pa.W[0] = wqb; pa.W[1] = wkb; pa.W[2] = wvb;
    pa.Bz[0] = bq; pa.Bz[1] = bk; pa.Bz[2] = bv;
    pa.Oz[0] = Qb; pa.Oz[1] = Kb; pa.Oz[2] = Vb;
    gemm_qkv<<<dim3(8, 64, 3), 256, 0, stream>>>(pa);

    attn_fwd<<<dim3(32, NH, 4), 256, 0, stream>>>(Qb, Kb, Vb, Ax);

    gemm_out<<<dim3(8, 64), 256, 0, stream>>>(Ax, wob, bo, Out);
}

// Round 6
// 352.777 us; speedup vs baseline: 1.1642x; 1.1642x over previous
//
#include <hip/hip_runtime.h>
#include <math.h>

// MHA forward: B=4, S=2048, E=1024, H=16, D=64. bf16 MFMA path.
// Round 6: attention = paired-uniform blocks (34 k-tiles each, 512 blocks,
// all-resident) with 128-row q-tiles: each wave handles TWO 16-row q-subtiles
// so K/V LDS frag reads are reused 2x (attn is LDS-throughput-bound).
// QKV stays all-bf16 (X pre-converted into d_out/Ax scratch), grid M-fast.

#define EMBED 1024
#define SEQ   2048
#define NH    16
#define HD    64
#define QSCALE 0.18033688011112042f   // 0.125 * log2(e), folded into Q proj

typedef __attribute__((ext_vector_type(4))) float f32x4;
typedef __attribute__((ext_vector_type(8))) short s16x8;
typedef __attribute__((ext_vector_type(4))) short s16x4;
typedef __attribute__((ext_vector_type(2))) unsigned int u32x2;

#define GLDS16(gp, lp) __builtin_amdgcn_global_load_lds( \
    (const __attribute__((address_space(1))) void*)(gp), \
    (__attribute__((address_space(3))) void*)(lp), 16, 0, 0)

__device__ __forceinline__ unsigned short f2bf(float f) {   // RNE
    unsigned int u = __builtin_bit_cast(unsigned int, f);
    u += 0x7fffu + ((u >> 16) & 1u);
    return (unsigned short)(u >> 16);
}
// pack two fp32 -> bf16x2 dword by truncation (1 v_perm_b32)
__device__ __forceinline__ unsigned int pkbf(float lo, float hi) {
    return __builtin_amdgcn_perm(__builtin_bit_cast(unsigned int, hi),
                                 __builtin_bit_cast(unsigned int, lo),
                                 0x07060302u);
}

// ---------------- fp32 -> bf16 (RNE): 3 X tensors + 4 weights ---------------
struct CvtArgs { const float* s[7]; unsigned short* d[7]; };
__global__ void cvt_all(CvtArgs ca)
{
    const int y = blockIdx.y;
    const int n4 = (y < 3) ? (1 << 21) : (1 << 18);   // f32x4 count
    int i = blockIdx.x * 256 + threadIdx.x;
    if (i < n4) {
        f32x4 v = *(const f32x4*)(ca.s[y] + (size_t)i * 4);
        s16x4 p;
        p[0] = (short)f2bf(v[0]); p[1] = (short)f2bf(v[1]);
        p[2] = (short)f2bf(v[2]); p[3] = (short)f2bf(v[3]);
        *(s16x4*)(ca.d[y] + (size_t)i * 4) = p;
    }
}

// ---------------- QKV projection (z = 0:Q, 1:K, 2:V), all-bf16 --------------
struct ProjArgs {
    const unsigned short* X[3];
    const unsigned short* W[3];
    const float* Bz[3];
    unsigned short* Oz[3];
};
__global__ void __launch_bounds__(256)
gemm_qkv(ProjArgs pa)
{
    __shared__ unsigned short Ab[128 * 64];
    __shared__ unsigned short Bb[128 * 64];
    const int z = blockIdx.z;
    const unsigned short* Xb = pa.X[z];
    const unsigned short* Wb = pa.W[z];
    const float* bias = pa.Bz[z];
    unsigned short* Out = pa.Oz[z];
    const float scale = (z == 0) ? QSCALE : 1.0f;
    const int tid = threadIdx.x, lane = tid & 63, wv = tid >> 6;
    const int g = lane >> 4, c = lane & 15;
    const int wx = wv & 1, wy = wv >> 1;
    const int bm0 = blockIdx.x * 128, bn0 = blockIdx.y * 128;  // M fast

    f32x4 acc[4][4];
#pragma unroll
    for (int i = 0; i < 4; ++i)
#pragma unroll
        for (int n = 0; n < 4; ++n) acc[i][n] = f32x4{0.f, 0.f, 0.f, 0.f};

    for (int k0 = 0; k0 < EMBED; k0 += 64) {
        __syncthreads();
#pragma unroll
        for (int cc = 0; cc < 4; ++cc) {
            int li = cc * 256 + tid;
            int row = li >> 3, ch = (li & 7) ^ (row & 7);
            GLDS16(Xb + (size_t)(bm0 + row) * EMBED + k0 + ch * 8,
                   Ab + cc * 2048 + wv * 512);
        }
#pragma unroll
        for (int cc = 0; cc < 4; ++cc) {
            int li = cc * 256 + tid;
            int row = li >> 3, ch = (li & 7) ^ (row & 7);
            GLDS16(Wb + (size_t)(bn0 + row) * EMBED + k0 + ch * 8,
                   Bb + cc * 2048 + wv * 512);
        }
        __syncthreads();
#pragma unroll
        for (int ks = 0; ks < 2; ++ks) {
            const int ib = ((ks * 4 + g) ^ (c & 7)) * 8;
            s16x8 af[4], bfr[4];
#pragma unroll
            for (int i = 0; i < 4; ++i)
                af[i] = *(const s16x8*)(&Ab[(wy * 64 + i * 16 + c) * 64 + ib]);
#pragma unroll
            for (int n = 0; n < 4; ++n)
                bfr[n] = *(const s16x8*)(&Bb[(wx * 64 + n * 16 + c) * 64 + ib]);
#pragma unroll
            for (int i = 0; i < 4; ++i)
#pragma unroll
                for (int n = 0; n < 4; ++n)
                    acc[i][n] = __builtin_amdgcn_mfma_f32_16x16x32_bf16(af[i], bfr[n], acc[i][n], 0, 0, 0);
        }
    }
    if (z < 2) {        // Q/K -> [B][H][S][D]
#pragma unroll
        for (int i = 0; i < 4; ++i) {
            int m0 = bm0 + wy * 64 + i * 16 + g * 4;
            int bb = m0 >> 11, s0 = m0 & 2047;
#pragma unroll
            for (int n = 0; n < 4; ++n) {
                int ncol = bn0 + wx * 64 + n * 16 + c;
                float bv = bias[ncol];
                int hh = ncol >> 6, dd = ncol & 63;
                size_t base = (((size_t)bb * NH + hh) * SEQ + s0) * HD + dd;
#pragma unroll
                for (int r = 0; r < 4; ++r)
                    Out[base + (size_t)r * HD] = f2bf((acc[i][n][r] + bv) * scale);
            }
        }
    } else {            // V -> V^T [B][H][D][S], 8B stores
#pragma unroll
        for (int i = 0; i < 4; ++i) {
            int m0 = bm0 + wy * 64 + i * 16 + g * 4;
            int bb = m0 >> 11, s0 = m0 & 2047;
#pragma unroll
            for (int n = 0; n < 4; ++n) {
                int ncol = bn0 + wx * 64 + n * 16 + c;
                float bv = bias[ncol];
                int hh = ncol >> 6, dd = ncol & 63;
                s16x4 pk;
#pragma unroll
                for (int r = 0; r < 4; ++r) pk[r] = (short)f2bf(acc[i][n][r] + bv);
                *(s16x4*)(&Out[(((size_t)bb * NH + hh) * HD + dd) * SEQ + s0]) = pk;
            }
        }
    }
}

// ---------------- output projection -----------------------------------------
__global__ void __launch_bounds__(256)
gemm_out(const unsigned short* __restrict__ Xb, const unsigned short* __restrict__ Wb,
         const float* __restrict__ bias, float* __restrict__ Out)
{
    __shared__ unsigned short Ab[128 * 64];
    __shared__ unsigned short Bb[128 * 64];
    const int tid = threadIdx.x;
    const int lane = tid & 63, wv = tid >> 6;
    const int g = lane >> 4, c = lane & 15;
    const int wx = wv & 1, wy = wv >> 1;
    const int bm0 = blockIdx.x * 128, bn0 = blockIdx.y * 128;  // M fast

    f32x4 acc[4][4];
#pragma unroll
    for (int i = 0; i < 4; ++i)
#pragma unroll
        for (int n = 0; n < 4; ++n) acc[i][n] = f32x4{0.f, 0.f, 0.f, 0.f};

    for (int k0 = 0; k0 < EMBED; k0 += 64) {
        __syncthreads();
#pragma unroll
        for (int cc = 0; cc < 4; ++cc) {
            int li = cc * 256 + tid;
            int row = li >> 3, ch = (li & 7) ^ (row & 7);
            GLDS16(Xb + (size_t)(bm0 + row) * EMBED + k0 + ch * 8,
                   Ab + cc * 2048 + wv * 512);
        }
#pragma unroll
        for (int cc = 0; cc < 4; ++cc) {
            int li = cc * 256 + tid;
            int row = li >> 3, ch = (li & 7) ^ (row & 7);
            GLDS16(Wb + (size_t)(bn0 + row) * EMBED + k0 + ch * 8,
                   Bb + cc * 2048 + wv * 512);
        }
        __syncthreads();
#pragma unroll
        for (int ks = 0; ks < 2; ++ks) {
            const int ib = ((ks * 4 + g) ^ (c & 7)) * 8;
            s16x8 af[4], bfr[4];
#pragma unroll
            for (int i = 0; i < 4; ++i)
                af[i] = *(const s16x8*)(&Ab[(wy * 64 + i * 16 + c) * 64 + ib]);
#pragma unroll
            for (int n = 0; n < 4; ++n)
                bfr[n] = *(const s16x8*)(&Bb[(wx * 64 + n * 16 + c) * 64 + ib]);
#pragma unroll
            for (int i = 0; i < 4; ++i)
#pragma unroll
                for (int n = 0; n < 4; ++n)
                    acc[i][n] = __builtin_amdgcn_mfma_f32_16x16x32_bf16(af[i], bfr[n], acc[i][n], 0, 0, 0);
        }
    }
#pragma unroll
    for (int i = 0; i < 4; ++i) {
#pragma unroll
        for (int n = 0; n < 4; ++n) {
            int ncol = bn0 + wx * 64 + n * 16 + c;
            float bv = bias[ncol];
#pragma unroll
            for (int r = 0; r < 4; ++r) {
                int m = bm0 + wy * 64 + i * 16 + g * 4 + r;
                Out[(size_t)m * EMBED + ncol] = acc[i][n][r] + bv;
            }
        }
    }
}

// ---------------- causal flash attention ------------------------------------
// grid (8, NH, B); block = 4 waves; part loop over q-tiles {15-bx, bx} of 128
// rows each -> exactly 34 k-tiles per block (uniform; 512 blocks all-resident).
// Wave wv owns q-subtiles u=0: rows q0+wv*16, u=1: rows q0+64+wv*16; K/V LDS
// frag reads are shared across the two subtiles (2x LDS-traffic reuse).
__global__ void __launch_bounds__(256)
attn_fwd(const unsigned short* __restrict__ Qb, const unsigned short* __restrict__ Kb,
         const unsigned short* __restrict__ Vg, unsigned short* __restrict__ Ob)
{
    __shared__ unsigned short Kt[2][4096];     // K tile [s][d], swizzled
    __shared__ unsigned short Vt[2][4096];     // V^T tile [d][s], swizzled
    __shared__ unsigned int   Pb_[4][2][16 * 36]; // per-wave/subtile P dwords
    const int tid = threadIdx.x, lane = tid & 63, wv = tid >> 6;
    const int g = lane >> 4, c = lane & 15;
    const int h = blockIdx.y, b = blockIdx.z;
    const size_t bh = (size_t)b * NH + h;
    const unsigned short* K0 = Kb + bh * SEQ * HD;
    const unsigned short* V0 = Vg + bh * HD * SEQ;
    const int x0 = (g ^ (c & 7)) * 8;          // swizzled chunk offsets
    const int x1 = ((4 + g) ^ (c & 7)) * 8;
    // hoisted staging source offsets (swizzled)
    const int li0 = tid, li1 = 256 + tid;
    const int kr0 = (li0 >> 3) * HD + (((li0 & 7) ^ ((li0 >> 3) & 7)) << 3);
    const int kr1 = (li1 >> 3) * HD + (((li1 & 7) ^ ((li1 >> 3) & 7)) << 3);
    const int vr0 = (li0 >> 3) * SEQ + (((li0 & 7) ^ ((li0 >> 3) & 7)) << 3);
    const int vr1 = (li1 >> 3) * SEQ + (((li1 & 7) ^ ((li1 >> 3) & 7)) << 3);

    for (int part = 0; part < 2; ++part) {
        const int qt = part ? blockIdx.x : (15 - blockIdx.x);  // 128-row q-tile
        const int q0 = qt * 128;
        const int ktn = 2 * qt + 2;            // number of 64-wide k-tiles
        s16x8 qf[2][2];
#pragma unroll
        for (int u = 0; u < 2; ++u) {
            const unsigned short* Qp = Qb + (bh * SEQ + q0 + u * 64 + wv * 16) * HD;
            qf[u][0] = *(const s16x8*)(Qp + c * HD + g * 8);
            qf[u][1] = *(const s16x8*)(Qp + c * HD + 32 + g * 8);
        }
        f32x4 o[2][4];
#pragma unroll
        for (int u = 0; u < 2; ++u)
#pragma unroll
            for (int dt = 0; dt < 4; ++dt) o[u][dt] = f32x4{0.f, 0.f, 0.f, 0.f};
        float m_run[2] = {-INFINITY, -INFINITY};
        float l_run[2] = {0.f, 0.f};

        __syncthreads();   // protect LDS buffers across parts
        {   // prologue: stage kt=0 into buffer 0
            GLDS16(K0 + kr0, &Kt[0][0] + wv * 512);
            GLDS16(K0 + kr1, &Kt[0][2048] + wv * 512);
            GLDS16(V0 + vr0, &Vt[0][0] + wv * 512);
            GLDS16(V0 + vr1, &Vt[0][2048] + wv * 512);
        }

        for (int kt = 0; kt < ktn; ++kt) {
            __syncthreads();           // publishes buffer kt&1 (drains GLDS)
            const int cur = kt & 1;
            if (kt + 1 < ktn) {        // prefetch kt+1 into the other buffer
                const int nxt = cur ^ 1;
                const unsigned short* Kg = K0 + (size_t)(kt + 1) * 64 * HD;
                GLDS16(Kg + kr0, &Kt[nxt][0] + wv * 512);
                GLDS16(Kg + kr1, &Kt[nxt][2048] + wv * 512);
                const unsigned short* Vp = V0 + (kt + 1) * 64;
                GLDS16(Vp + vr0, &Vt[nxt][0] + wv * 512);
                GLDS16(Vp + vr1, &Vt[nxt][2048] + wv * 512);
            }
            const unsigned short* Kc = &Kt[cur][0];
            const unsigned short* Vc = &Vt[cur][0];

            const int d0 = 2 * qt;                 // diag tile for subtile 0
            const bool act0 = (kt <= d0);          // subtile-0 active this tile
            const int ntm0 = (kt == d0) ? wv : 3;
            const int ntm1 = (kt == d0 + 1) ? wv : 3;
            const int ntl = act0 ? 3 : ntm1;       // highest nt needing K frags

            f32x4 sc[2][4];
#pragma unroll
            for (int nt = 0; nt < 4; ++nt) {
                if (nt <= ntl) {
                    s16x8 kf0 = *(const s16x8*)(&Kc[(nt * 16 + c) * 64 + x0]);
                    s16x8 kf1 = *(const s16x8*)(&Kc[(nt * 16 + c) * 64 + x1]);
                    if (act0 && nt <= ntm0) {
                        f32x4 a = f32x4{0.f, 0.f, 0.f, 0.f};
                        a = __builtin_amdgcn_mfma_f32_16x16x32_bf16(kf0, qf[0][0], a, 0, 0, 0);
                        a = __builtin_amdgcn_mfma_f32_16x16x32_bf16(kf1, qf[0][1], a, 0, 0, 0);
                        sc[0][nt] = a;
                    } else {
                        sc[0][nt] = f32x4{-INFINITY, -INFINITY, -INFINITY, -INFINITY};
                    }
                    if (nt <= ntm1) {
                        f32x4 a = f32x4{0.f, 0.f, 0.f, 0.f};
                        a = __builtin_amdgcn_mfma_f32_16x16x32_bf16(kf0, qf[1][0], a, 0, 0, 0);
                        a = __builtin_amdgcn_mfma_f32_16x16x32_bf16(kf1, qf[1][1], a, 0, 0, 0);
                        sc[1][nt] = a;
                    } else {
                        sc[1][nt] = f32x4{-INFINITY, -INFINITY, -INFINITY, -INFINITY};
                    }
                } else {
                    sc[0][nt] = f32x4{-INFINITY, -INFINITY, -INFINITY, -INFINITY};
                    sc[1][nt] = f32x4{-INFINITY, -INFINITY, -INFINITY, -INFINITY};
                }
            }
#pragma unroll
            for (int u = 0; u < 2; ++u) {
                if (u == 0 && !act0) continue;
                if (kt == d0 + u) {   // diagonal tile for this subtile
#pragma unroll
                    for (int nt = 0; nt < 4; ++nt)
#pragma unroll
                        for (int r = 0; r < 4; ++r)
                            if (nt * 16 + g * 4 + r > wv * 16 + c)
                                sc[u][nt][r] = -INFINITY;
                }
                // online softmax: lane owns q-column c; k spread over regs+g
                float mloc = -INFINITY;
#pragma unroll
                for (int nt = 0; nt < 4; ++nt)
                    mloc = fmaxf(mloc, fmaxf(fmaxf(sc[u][nt][0], sc[u][nt][1]),
                                             fmaxf(sc[u][nt][2], sc[u][nt][3])));
                mloc = fmaxf(mloc, __shfl_xor(mloc, 16));
                mloc = fmaxf(mloc, __shfl_xor(mloc, 32));
                if (__any(mloc > m_run[u])) {
                    float mnew = fmaxf(m_run[u], mloc);
                    float alpha = __builtin_amdgcn_exp2f(m_run[u] - mnew);
                    m_run[u] = mnew;
                    l_run[u] *= alpha;
                    float av[4];
#pragma unroll
                    for (int r = 0; r < 4; ++r) av[r] = __shfl(alpha, g * 4 + r, 16);
#pragma unroll
                    for (int dt = 0; dt < 4; ++dt)
#pragma unroll
                        for (int r = 0; r < 4; ++r) o[u][dt][r] *= av[r];
                }
                float rs = 0.f;
#pragma unroll
                for (int nt = 0; nt < 4; ++nt)
#pragma unroll
                    for (int r = 0; r < 4; ++r) {
                        float p = __builtin_amdgcn_exp2f(sc[u][nt][r] - m_run[u]);
                        sc[u][nt][r] = p;
                        rs += p;
                    }
                rs += __shfl_xor(rs, 16);
                rs += __shfl_xor(rs, 32);
                l_run[u] += rs;
                // P^T (C-layout) -> A-layout via wave-private packed LDS
                unsigned int* Pw = &Pb_[wv][u][0];
#pragma unroll
                for (int nt = 0; nt < 4; ++nt) {
                    u32x2 w;
                    w[0] = pkbf(sc[u][nt][0], sc[u][nt][1]);
                    w[1] = pkbf(sc[u][nt][2], sc[u][nt][3]);
                    *(u32x2*)(&Pw[c * 36 + nt * 8 + g * 2]) = w;
                }
            }
            // O += P V, V frags shared across the two subtiles
#pragma unroll
            for (int kc = 0; kc < 2; ++kc) {
                const int xv = kc ? x1 : x0;
                s16x8 pf0, pf1;
                if (act0) pf0 = *(const s16x8*)(&Pb_[wv][0][c * 36 + kc * 16 + g * 4]);
                pf1 = *(const s16x8*)(&Pb_[wv][1][c * 36 + kc * 16 + g * 4]);
#pragma unroll
                for (int dt = 0; dt < 4; ++dt) {
                    s16x8 vf = *(const s16x8*)(&Vc[(dt * 16 + c) * 64 + xv]);
                    if (act0)
                        o[0][dt] = __builtin_amdgcn_mfma_f32_16x16x32_bf16(pf0, vf, o[0][dt], 0, 0, 0);
                    o[1][dt] = __builtin_amdgcn_mfma_f32_16x16x32_bf16(pf1, vf, o[1][dt], 0, 0, 0);
                }
            }
        }
        // epilogue: normalize rows, write [B][S][E] bf16
#pragma unroll
        for (int u = 0; u < 2; ++u) {
            float linv = 1.0f / l_run[u];
            float lv[4];
#pragma unroll
            for (int r = 0; r < 4; ++r) lv[r] = __shfl(linv, g * 4 + r, 16);
#pragma unroll
            for (int r = 0; r < 4; ++r) {
                int srow = q0 + u * 64 + wv * 16 + g * 4 + r;
                size_t base = ((size_t)b * SEQ + srow) * EMBED + h * HD;
#pragma unroll
                for (int dt = 0; dt < 4; ++dt)
                    Ob[base + dt * 16 + c] = f2bf(o[u][dt][r] * lv[r]);
            }
        }
    }
}

extern "C" void kernel_launch(void* const* d_in, const int* in_sizes, int n_in,
                              void* d_out, int out_size, void* d_ws, size_t ws_size,
                              hipStream_t stream)
{
    (void)in_sizes; (void)n_in; (void)out_size; (void)ws_size;
    const float* Xq = (const float*)d_in[0];
    const float* Xk = (const float*)d_in[1];
    const float* Xv = (const float*)d_in[2];
    // d_in[3] = attn_mask: tril(ones) -> causal handled analytically
    const float* Wq = (const float*)d_in[4];
    const float* bq = (const float*)d_in[5];
    const float* Wk = (const float*)d_in[6];
    const float* bk = (const float*)d_in[7];
    const float* Wv = (const float*)d_in[8];
    const float* bv = (const float*)d_in[9];
    const float* Wo = (const float*)d_in[10];
    const float* bo = (const float*)d_in[11];
    float* Out = (float*)d_out;

    unsigned short* ws = (unsigned short*)d_ws;
    unsigned short* wqb = ws;                    // 4 x 1M elts (weights bf16)
    unsigned short* wkb = wqb + 1048576;
    unsigned short* wvb = wkb + 1048576;
    unsigned short* wob = wvb + 1048576;
    unsigned short* Qb  = wob + 1048576;         // [B][H][S][D] bf16
    unsigned short* Kb  = Qb + 8388608;          // [B][H][S][D] bf16
    unsigned short* Vb  = Kb + 8388608;          // [B][H][D][S] bf16 (V^T)
    unsigned short* Ax  = Vb + 8388608;          // attn out bf16 [B][S][E] / Xv_b
    // bf16 X scratch overlaid on d_out (dead until gemm_out) and Ax (dead
    // until attn): Xq_b = d_out[0:8M], Xk_b = d_out[8M:16M], Xv_b = Ax.
    unsigned short* Xqb = (unsigned short*)d_out;
    unsigned short* Xkb = Xqb + 8388608;
    unsigned short* Xvb = Ax;

    CvtArgs ca;
    ca.s[0] = Xq; ca.s[1] = Xk; ca.s[2] = Xv;
    ca.s[3] = Wq; ca.s[4] = Wk; ca.s[5] = Wv; ca.s[6] = Wo;
    ca.d[0] = Xqb; ca.d[1] = Xkb; ca.d[2] = Xvb;
    ca.d[3] = wqb; ca.d[4] = wkb; ca.d[5] = wvb; ca.d[6] = wob;
    cvt_all<<<dim3(8192, 7), 256, 0, stream>>>(ca);

    ProjArgs pa;
    pa.X[0] = Xqb; pa.X[1] = Xkb; pa.X[2] = Xvb;
    pa.W[0] = wqb; pa.W[1] = wkb; pa.W[2] = wvb;
    pa.Bz[0] = bq; pa.Bz[1] = bk; pa.Bz[2] = bv;
    pa.Oz[0] = Qb; pa.Oz[1] = Kb; pa.Oz[2] = Vb;
    gemm_qkv<<<dim3(64, 8, 3), 256, 0, stream>>>(pa);

    attn_fwd<<<dim3(8, NH, 4), 256, 0, stream>>>(Qb, Kb, Vb, Ax);

    gemm_out<<<dim3(64, 8), 256, 0, stream>>>(Ax, wob, bo, Out);
}